// Round 1
// baseline (291.127 us; speedup 1.0000x reference)
//
#include <hip/hip_runtime.h>
#include <math.h>

#define HH 64
#define WW 64
#define CH 256
#define NB 2
#define HWSZ (HH*WW)        // 4096
#define PIX (NB*HWSZ)       // 8192

// ---------------- NCHW -> NHWC transpose ----------------
__global__ __launch_bounds__(256) void k_nchw2nhwc(const float* __restrict__ in, float* __restrict__ out){
  __shared__ float t[32][33];
  int n = blockIdx.z;
  int p0 = blockIdx.x * 32;   // spatial index base
  int c0 = blockIdx.y * 32;   // channel base
  const float* inn = in + (size_t)n * CH * HWSZ;
  float* outn = out + (size_t)n * HWSZ * CH;
  int tx = threadIdx.x, ty = threadIdx.y; // 32 x 8
  #pragma unroll
  for (int i = 0; i < 4; ++i) {
    int c = c0 + ty + i*8;
    t[ty + i*8][tx] = inn[(size_t)c * HWSZ + p0 + tx];   // t[c_local][p_local]
  }
  __syncthreads();
  #pragma unroll
  for (int i = 0; i < 4; ++i) {
    int p = p0 + ty + i*8;
    outn[(size_t)p * CH + c0 + tx] = t[tx][ty + i*8];    // out[p][c] ; c_local = tx
  }
}

// ---------------- concat offset/mask weights into [256][256] (cols 216..255 zero) ----------------
__global__ __launch_bounds__(256) void k_concat(const float* __restrict__ off_w, const float* __restrict__ off_b,
                                                const float* __restrict__ mk_w, const float* __restrict__ mk_b,
                                                float* __restrict__ Bcat, float* __restrict__ bcat){
  int r = blockIdx.x;        // 0..255 (K row)
  int col = threadIdx.x;     // 0..255
  float val = (col < 144) ? off_w[r*144 + col] : ((col < 216) ? mk_w[r*72 + (col-144)] : 0.f);
  Bcat[r*256 + col] = val;
  if (r == 0) bcat[col] = (col < 144) ? off_b[col] : ((col < 216) ? mk_b[col-144] : 0.f);
}

// ---------------- fused depthwise 3x3 + LayerNorm + GELU ----------------
__global__ __launch_bounds__(256) void k_dwln(const float* __restrict__ xin,
    const float* __restrict__ dw_w, const float* __restrict__ dw_b,
    const float* __restrict__ ln_g, const float* __restrict__ ln_b,
    float* __restrict__ f){
  __shared__ float p1[4], p2[4];
  int pix = blockIdx.x;
  int c = threadIdx.x;
  int n  = pix >> 12;
  int hw = pix & 4095;
  int h = hw >> 6, w = hw & 63;
  const float* xb = xin + (size_t)n * HWSZ * CH;
  float s = dw_b[c];
  #pragma unroll
  for (int i = 0; i < 3; ++i) {
    int y = h + i - 1;
    if ((unsigned)y < 64u) {
      #pragma unroll
      for (int j = 0; j < 3; ++j) {
        int x = w + j - 1;
        if ((unsigned)x < 64u)
          s = fmaf(xb[((size_t)((y<<6)+x))*CH + c], dw_w[(i*3+j)*CH + c], s);
      }
    }
  }
  float v1 = s, v2 = s*s;
  #pragma unroll
  for (int off = 32; off >= 1; off >>= 1) {
    v1 += __shfl_xor(v1, off);
    v2 += __shfl_xor(v2, off);
  }
  int wid = c >> 6, lane = c & 63;
  if (lane == 0) { p1[wid] = v1; p2[wid] = v2; }
  __syncthreads();
  float S1 = p1[0]+p1[1]+p1[2]+p1[3];
  float S2 = p2[0]+p2[1]+p2[2]+p2[3];
  float mean = S1 * (1.f/256.f);
  float var  = S2 * (1.f/256.f) - mean*mean;
  float inv  = rsqrtf(var + 1e-5f);
  float z = (s - mean) * inv * ln_g[c] + ln_b[c];
  float ge = 0.5f * z * (1.f + erff(z * 0.70710678118654752f));
  f[(size_t)pix*CH + c] = ge;
}

// ---------------- fp32 GEMM: C[8192,256] = A[8192,256] @ B[256,256] + bias ----------------
__global__ __launch_bounds__(256) void k_gemm(const float* __restrict__ A, const float* __restrict__ B,
                                              const float* __restrict__ bias, float* __restrict__ C){
  __shared__ float As[16][64];   // [k][row]
  __shared__ float Bs[16][64];   // [k][col]
  int tid = threadIdx.x;
  int tx = tid & 15, ty = tid >> 4;
  int rowBase = blockIdx.x * 64;
  int colBase = blockIdx.y * 64;
  int la_row = tid >> 2;          // 0..63
  int la_k4  = (tid & 3) << 2;    // 0,4,8,12
  int lb_r   = tid >> 4;          // 0..15
  int lb_c   = (tid & 15) << 2;   // 0..60
  float acc[4][4] = {};
  for (int k0 = 0; k0 < 256; k0 += 16) {
    float4 av = *reinterpret_cast<const float4*>(A + (size_t)(rowBase + la_row) * 256 + k0 + la_k4);
    float4 bv = *reinterpret_cast<const float4*>(B + (size_t)(k0 + lb_r) * 256 + colBase + lb_c);
    __syncthreads();
    As[la_k4 + 0][la_row] = av.x;
    As[la_k4 + 1][la_row] = av.y;
    As[la_k4 + 2][la_row] = av.z;
    As[la_k4 + 3][la_row] = av.w;
    *reinterpret_cast<float4*>(&Bs[lb_r][lb_c]) = bv;
    __syncthreads();
    #pragma unroll
    for (int k = 0; k < 16; ++k) {
      float4 a = *reinterpret_cast<const float4*>(&As[k][ty << 2]);
      float4 b = *reinterpret_cast<const float4*>(&Bs[k][tx << 2]);
      float aa[4] = {a.x, a.y, a.z, a.w};
      float bb[4] = {b.x, b.y, b.z, b.w};
      #pragma unroll
      for (int i = 0; i < 4; ++i)
        #pragma unroll
        for (int j = 0; j < 4; ++j)
          acc[i][j] = fmaf(aa[i], bb[j], acc[i][j]);
    }
  }
  #pragma unroll
  for (int i = 0; i < 4; ++i) {
    int row = rowBase + (ty << 2) + i;
    #pragma unroll
    for (int j = 0; j < 4; ++j) {
      int col = colBase + (tx << 2) + j;
      C[(size_t)row * 256 + col] = acc[i][j] + bias[col];
    }
  }
}

// ---------------- deformable sampling + softmax(mask) + aggregate ----------------
// fm layout per pixel (256 cols): [0..143] offsets (g*18 + k*2 + {x,y}), [144..215] mask logits (144 + g*9 + k)
__global__ __launch_bounds__(256) void k_sample(const float* __restrict__ v,
    const float* __restrict__ fm, float* __restrict__ o){
  int pix = blockIdx.x;
  int tid = threadIdx.x;         // channel = g*32 + ch
  int g = tid >> 5;
  int n  = pix >> 12;
  int hw = pix & 4095;
  int h = hw >> 6, w = hw & 63;
  const float* fmr = fm + (size_t)pix * 256;
  float ml[9];
  float mx = -1e30f;
  #pragma unroll
  for (int k = 0; k < 9; ++k) { ml[k] = fmr[144 + g*9 + k]; mx = fmaxf(mx, ml[k]); }
  float ssum = 0.f;
  #pragma unroll
  for (int k = 0; k < 9; ++k) { ml[k] = __expf(ml[k] - mx); ssum += ml[k]; }
  float inv = 1.f / ssum;
  const float* vb = v + (size_t)n * HWSZ * CH + tid;
  float acc = 0.f;
  #pragma unroll
  for (int k = 0; k < 9; ++k) {
    int dx = k/3 - 1, dy = k%3 - 1;     // dx-major per meshgrid(indexing='ij')
    float ox = fmr[g*18 + k*2];
    float oy = fmr[g*18 + k*2 + 1];
    float xu = (float)(w + dx) + ox;    // unpadded sampling coords
    float yu = (float)(h + dy) + oy;
    float xf = floorf(xu), yf = floorf(yu);
    float tx = xu - xf, ty = yu - yf;
    int x0 = (int)xf, y0 = (int)yf;
    float val = 0.f;
    bool vx0 = (unsigned)x0 < 64u, vx1 = (unsigned)(x0+1) < 64u;
    bool vy0 = (unsigned)y0 < 64u, vy1 = (unsigned)(y0+1) < 64u;
    if (vy0) {
      if (vx0) val = fmaf(vb[(size_t)((y0<<6) + x0)*CH],     (1.f-tx)*(1.f-ty), val);
      if (vx1) val = fmaf(vb[(size_t)((y0<<6) + x0 + 1)*CH], tx*(1.f-ty),       val);
    }
    if (vy1) {
      if (vx0) val = fmaf(vb[(size_t)(((y0+1)<<6) + x0)*CH],     (1.f-tx)*ty, val);
      if (vx1) val = fmaf(vb[(size_t)(((y0+1)<<6) + x0 + 1)*CH], tx*ty,       val);
    }
    acc = fmaf(ml[k], val, acc);
  }
  o[(size_t)pix*CH + tid] = acc * inv;
}

// ---------------- gate: out[n,c,h,w] = x[n,c,h,w] * attn[n,h,w,c] ----------------
__global__ __launch_bounds__(256) void k_gate(const float* __restrict__ x, const float* __restrict__ attn,
                                              float* __restrict__ out){
  __shared__ float t[32][33];
  int n = blockIdx.z;
  int p0 = blockIdx.x * 32;
  int c0 = blockIdx.y * 32;
  const float* an = attn + (size_t)n * HWSZ * CH;
  const float* xn = x + (size_t)n * CH * HWSZ;
  float* on = out + (size_t)n * CH * HWSZ;
  int tx = threadIdx.x, ty = threadIdx.y;
  #pragma unroll
  for (int i = 0; i < 4; ++i) {
    int p = p0 + ty + i*8;
    t[ty + i*8][tx] = an[(size_t)p * CH + c0 + tx];   // t[p_local][c_local]
  }
  __syncthreads();
  #pragma unroll
  for (int i = 0; i < 4; ++i) {
    int c = c0 + ty + i*8;
    size_t idx = (size_t)c * HWSZ + p0 + tx;
    on[idx] = xn[idx] * t[tx][ty + i*8];              // t[p_local=tx][c_local]
  }
}

extern "C" void kernel_launch(void* const* d_in, const int* in_sizes, int n_in,
                              void* d_out, int out_size, void* d_ws, size_t ws_size,
                              hipStream_t stream) {
  const float* x      = (const float*)d_in[0];
  const float* a_dw_w = (const float*)d_in[1];
  const float* a_dw_b = (const float*)d_in[2];
  const float* a_ln_g = (const float*)d_in[3];
  const float* a_ln_b = (const float*)d_in[4];
  const float* a_in_w = (const float*)d_in[5];
  const float* a_in_b = (const float*)d_in[6];
  const float* a_off_w= (const float*)d_in[7];
  const float* a_off_b= (const float*)d_in[8];
  const float* a_mk_w = (const float*)d_in[9];
  const float* a_mk_b = (const float*)d_in[10];
  const float* a_out_w= (const float*)d_in[11];
  const float* a_out_b= (const float*)d_in[12];
  const float* b_dw_w = (const float*)d_in[13];
  const float* b_dw_b = (const float*)d_in[14];
  const float* b_ln_g = (const float*)d_in[15];
  const float* b_ln_b = (const float*)d_in[16];
  const float* b_in_w = (const float*)d_in[17];
  const float* b_in_b = (const float*)d_in[18];
  const float* b_off_w= (const float*)d_in[19];
  const float* b_off_b= (const float*)d_in[20];
  const float* b_mk_w = (const float*)d_in[21];
  const float* b_mk_b = (const float*)d_in[22];
  const float* b_out_w= (const float*)d_in[23];
  const float* b_out_b= (const float*)d_in[24];
  const float* proj_w = (const float*)d_in[25];
  const float* proj_b = (const float*)d_in[26];
  float* out = (float*)d_out;

  float* ws = (float*)d_ws;
  const size_t BUF = (size_t)PIX * CH;   // 2,097,152 floats (8 MB)
  float* buf0 = ws;               // x NHWC -> later attn2
  float* buf1 = buf0 + BUF;       // f -> later proj output
  float* buf2 = buf1 + BUF;       // v
  float* buf3 = buf2 + BUF;       // fm (offset+mask logits)
  float* buf4 = buf3 + BUF;       // o (sampled)
  float* buf5 = buf4 + BUF;       // attn1
  float* BcatA = buf5 + BUF;
  float* bcatA = BcatA + 256*256;
  float* BcatB = bcatA + 256;
  float* bcatB = BcatB + 256*256;

  dim3 tb(32, 8);
  dim3 tgrid(HWSZ/32, CH/32, NB);
  dim3 ggrid(PIX/64, 4);

  k_nchw2nhwc<<<tgrid, tb, 0, stream>>>(x, buf0);
  k_concat<<<256, 256, 0, stream>>>(a_off_w, a_off_b, a_mk_w, a_mk_b, BcatA, bcatA);
  k_concat<<<256, 256, 0, stream>>>(b_off_w, b_off_b, b_mk_w, b_mk_b, BcatB, bcatB);

  // ---- layer a ----
  k_dwln<<<PIX, 256, 0, stream>>>(buf0, a_dw_w, a_dw_b, a_ln_g, a_ln_b, buf1);
  k_gemm<<<ggrid, 256, 0, stream>>>(buf0, a_in_w, a_in_b, buf2);    // v
  k_gemm<<<ggrid, 256, 0, stream>>>(buf1, BcatA, bcatA, buf3);      // offsets+mask logits
  k_sample<<<PIX, 256, 0, stream>>>(buf2, buf3, buf4);              // o
  k_gemm<<<ggrid, 256, 0, stream>>>(buf4, a_out_w, a_out_b, buf5);  // attn1

  // ---- layer b ----
  k_dwln<<<PIX, 256, 0, stream>>>(buf5, b_dw_w, b_dw_b, b_ln_g, b_ln_b, buf1);
  k_gemm<<<ggrid, 256, 0, stream>>>(buf5, b_in_w, b_in_b, buf2);    // v
  k_gemm<<<ggrid, 256, 0, stream>>>(buf1, BcatB, bcatB, buf3);      // offsets+mask logits
  k_sample<<<PIX, 256, 0, stream>>>(buf2, buf3, buf4);              // o
  k_gemm<<<ggrid, 256, 0, stream>>>(buf4, b_out_w, b_out_b, buf0);  // attn2

  // ---- final proj + gate ----
  k_gemm<<<ggrid, 256, 0, stream>>>(buf0, proj_w, proj_b, buf1);    // attn
  k_gate<<<tgrid, tb, 0, stream>>>(x, buf1, out);
}

// Round 2
// 150.811 us; speedup vs baseline: 1.9304x; 1.9304x over previous
//
#include <hip/hip_runtime.h>
#include <hip/hip_bf16.h>
#include <math.h>

#define HH 64
#define WW 64
#define CH 256
#define NB 2
#define HWSZ (HH*WW)        // 4096
#define PIX (NB*HWSZ)       // 8192
#define PPB 4               // pixels per block in k_sample

typedef __attribute__((ext_vector_type(8))) short bf16x8;
typedef __attribute__((ext_vector_type(4))) float f32x4;

static __device__ __forceinline__ ushort f2bf(float f){
  union { __hip_bfloat16 h; ushort u; } cv;
  cv.h = __float2bfloat16(f);   // round-to-nearest-even
  return cv.u;
}

// ---------------- NCHW -> NHWC transpose ----------------
__global__ __launch_bounds__(256) void k_nchw2nhwc(const float* __restrict__ in, float* __restrict__ out){
  __shared__ float t[32][33];
  int n = blockIdx.z;
  int p0 = blockIdx.x * 32;   // spatial index base
  int c0 = blockIdx.y * 32;   // channel base
  const float* inn = in + (size_t)n * CH * HWSZ;
  float* outn = out + (size_t)n * HWSZ * CH;
  int tx = threadIdx.x, ty = threadIdx.y; // 32 x 8
  #pragma unroll
  for (int i = 0; i < 4; ++i) {
    int c = c0 + ty + i*8;
    t[ty + i*8][tx] = inn[(size_t)c * HWSZ + p0 + tx];   // t[c_local][p_local]
  }
  __syncthreads();
  #pragma unroll
  for (int i = 0; i < 4; ++i) {
    int p = p0 + ty + i*8;
    outn[(size_t)p * CH + c0 + tx] = t[tx][ty + i*8];    // out[p][c] ; c_local = tx
  }
}

// ---------------- weight prep: fp32 [k][n] -> bf16 B^T [n][k] (k contiguous) ----------------
// z: 0=a_in 1=a_cat 2=a_out 3=b_in 4=b_cat 5=b_out 6=proj
__global__ __launch_bounds__(256) void k_prepw(const float* __restrict__ a_in_w, const float* __restrict__ a_off_w,
    const float* __restrict__ a_mk_w, const float* __restrict__ a_out_w,
    const float* __restrict__ b_in_w, const float* __restrict__ b_off_w,
    const float* __restrict__ b_mk_w, const float* __restrict__ b_out_w,
    const float* __restrict__ proj_w, ushort* __restrict__ Bt){
  __shared__ float t[32][33];
  int z = blockIdx.z;
  int n0 = blockIdx.x * 32, k0 = blockIdx.y * 32;
  int tx = threadIdx.x, ty = threadIdx.y;
  const float* W = a_in_w; int mode = 0;
  switch(z){
    case 0: W = a_in_w; break;
    case 1: mode = 1; break;
    case 2: W = a_out_w; break;
    case 3: W = b_in_w; break;
    case 4: mode = 2; break;
    case 5: W = b_out_w; break;
    default: W = proj_w; break;
  }
  #pragma unroll
  for (int i = 0; i < 4; ++i) {
    int k = k0 + ty + i*8, nn = n0 + tx;
    float val;
    if (mode == 0) val = W[k*256 + nn];
    else {
      const float* ow = (mode == 1) ? a_off_w : b_off_w;
      const float* mw = (mode == 1) ? a_mk_w  : b_mk_w;
      val = (nn < 144) ? ow[k*144 + nn] : ((nn < 216) ? mw[k*72 + nn - 144] : 0.f);
    }
    t[ty + i*8][tx] = val;   // t[k_local][n_local]
  }
  __syncthreads();
  #pragma unroll
  for (int i = 0; i < 4; ++i) {
    int nn = n0 + ty + i*8, k = k0 + tx;
    Bt[(size_t)z*65536 + nn*256 + k] = f2bf(t[tx][ty + i*8]);
  }
}

// ---------------- bias concat ----------------
__global__ __launch_bounds__(256) void k_bias(const float* __restrict__ a_off_b, const float* __restrict__ a_mk_b,
    const float* __restrict__ b_off_b, const float* __restrict__ b_mk_b,
    float* __restrict__ bcatA, float* __restrict__ bcatB){
  int t = threadIdx.x;
  bcatA[t] = (t < 144) ? a_off_b[t] : ((t < 216) ? a_mk_b[t-144] : 0.f);
  bcatB[t] = (t < 144) ? b_off_b[t] : ((t < 216) ? b_mk_b[t-144] : 0.f);
}

// ---------------- fused depthwise 3x3 + LayerNorm + GELU ----------------
__global__ __launch_bounds__(256) void k_dwln(const float* __restrict__ xin,
    const float* __restrict__ dw_w, const float* __restrict__ dw_b,
    const float* __restrict__ ln_g, const float* __restrict__ ln_b,
    float* __restrict__ f){
  __shared__ float p1[4], p2[4];
  int pix = blockIdx.x;
  int c = threadIdx.x;
  int n  = pix >> 12;
  int hw = pix & 4095;
  int h = hw >> 6, w = hw & 63;
  const float* xb = xin + (size_t)n * HWSZ * CH;
  float s = dw_b[c];
  #pragma unroll
  for (int i = 0; i < 3; ++i) {
    int y = h + i - 1;
    if ((unsigned)y < 64u) {
      #pragma unroll
      for (int j = 0; j < 3; ++j) {
        int x = w + j - 1;
        if ((unsigned)x < 64u)
          s = fmaf(xb[((size_t)((y<<6)+x))*CH + c], dw_w[(i*3+j)*CH + c], s);
      }
    }
  }
  float v1 = s, v2 = s*s;
  #pragma unroll
  for (int off = 32; off >= 1; off >>= 1) {
    v1 += __shfl_xor(v1, off);
    v2 += __shfl_xor(v2, off);
  }
  int wid = c >> 6, lane = c & 63;
  if (lane == 0) { p1[wid] = v1; p2[wid] = v2; }
  __syncthreads();
  float S1 = p1[0]+p1[1]+p1[2]+p1[3];
  float S2 = p2[0]+p2[1]+p2[2]+p2[3];
  float mean = S1 * (1.f/256.f);
  float var  = S2 * (1.f/256.f) - mean*mean;
  float inv  = rsqrtf(var + 1e-5f);
  float z = (s - mean) * inv * ln_g[c] + ln_b[c];
  float ge = 0.5f * z * (1.f + erff(z * 0.70710678118654752f));
  f[(size_t)pix*CH + c] = ge;
}

// ---------------- bf16 MFMA GEMM: C[8192,256] = A[8192,256] @ B[256,256] + bias ----------------
// A fp32 (converted in staging), Bt bf16 pre-transposed [n][k]. BM=BN=BK=64, 4 waves x (32x32).
__global__ __launch_bounds__(256) void k_gemm_bf(const float* __restrict__ A, const ushort* __restrict__ Bt,
                                                 const float* __restrict__ bias, float* __restrict__ C){
  __shared__ ushort As[64*64];   // [row][k] bf16, XOR-swizzled
  __shared__ ushort Bs[64*64];   // [col][k] bf16, XOR-swizzled
  int tid = threadIdx.x;
  int rB = blockIdx.x * 64, cB = blockIdx.y * 64;
  int w = tid >> 6, l = tid & 63;
  int wm = w & 1, wn = w >> 1;
  int srow = tid >> 2;            // 0..63
  int skq  = (tid & 3) << 4;      // 0,16,32,48
  f32x4 acc[2][2] = {};
  for (int k0 = 0; k0 < 256; k0 += 64) {
    const float* Ap = A + (size_t)(rB + srow) * 256 + k0 + skq;
    float4 a0 = *reinterpret_cast<const float4*>(Ap);
    float4 a1 = *reinterpret_cast<const float4*>(Ap + 4);
    float4 a2 = *reinterpret_cast<const float4*>(Ap + 8);
    float4 a3 = *reinterpret_cast<const float4*>(Ap + 12);
    const ushort* Bp = Bt + (size_t)(cB + srow) * 256 + k0 + skq;
    uint4 b01 = *reinterpret_cast<const uint4*>(Bp);
    uint4 b23 = *reinterpret_cast<const uint4*>(Bp + 8);
    __syncthreads();
    union { ushort u[16]; uint4 q[2]; } pk;
    pk.u[0]=f2bf(a0.x); pk.u[1]=f2bf(a0.y); pk.u[2]=f2bf(a0.z); pk.u[3]=f2bf(a0.w);
    pk.u[4]=f2bf(a1.x); pk.u[5]=f2bf(a1.y); pk.u[6]=f2bf(a1.z); pk.u[7]=f2bf(a1.w);
    pk.u[8]=f2bf(a2.x); pk.u[9]=f2bf(a2.y); pk.u[10]=f2bf(a2.z); pk.u[11]=f2bf(a2.w);
    pk.u[12]=f2bf(a3.x); pk.u[13]=f2bf(a3.y); pk.u[14]=f2bf(a3.z); pk.u[15]=f2bf(a3.w);
    int swz = (srow & 7) << 3;
    *reinterpret_cast<uint4*>(&As[((srow << 6) + skq    ) ^ swz]) = pk.q[0];
    *reinterpret_cast<uint4*>(&As[((srow << 6) + skq + 8) ^ swz]) = pk.q[1];
    *reinterpret_cast<uint4*>(&Bs[((srow << 6) + skq    ) ^ swz]) = b01;
    *reinterpret_cast<uint4*>(&Bs[((srow << 6) + skq + 8) ^ swz]) = b23;
    __syncthreads();
    #pragma unroll
    for (int kk = 0; kk < 64; kk += 32) {
      int lk = kk + ((l >> 4) << 3);     // this lane's k chunk (8 elems)
      bf16x8 af[2], bfr[2];
      #pragma unroll
      for (int mi = 0; mi < 2; ++mi) {
        int row = wm*32 + mi*16 + (l & 15);
        af[mi] = *reinterpret_cast<const bf16x8*>(&As[((row << 6) + lk) ^ ((row & 7) << 3)]);
      }
      #pragma unroll
      for (int ni = 0; ni < 2; ++ni) {
        int col = wn*32 + ni*16 + (l & 15);
        bfr[ni] = *reinterpret_cast<const bf16x8*>(&Bs[((col << 6) + lk) ^ ((col & 7) << 3)]);
      }
      #pragma unroll
      for (int mi = 0; mi < 2; ++mi)
        #pragma unroll
        for (int ni = 0; ni < 2; ++ni)
          acc[mi][ni] = __builtin_amdgcn_mfma_f32_16x16x32_bf16(af[mi], bfr[ni], acc[mi][ni], 0, 0, 0);
    }
  }
  #pragma unroll
  for (int mi = 0; mi < 2; ++mi) {
    #pragma unroll
    for (int ni = 0; ni < 2; ++ni) {
      int row = rB + wm*32 + mi*16 + ((l >> 4) << 2);
      int col = cB + wn*32 + ni*16 + (l & 15);
      float bv = bias[col];
      #pragma unroll
      for (int j = 0; j < 4; ++j)
        C[(size_t)(row + j) * 256 + col] = acc[mi][ni][j] + bv;
    }
  }
}

// ---------------- deformable sampling + softmax(mask) + aggregate ----------------
// fm layout per pixel (256 cols): [0..143] offsets (g*18 + k*2 + {x,y}), [144..215] mask logits
__global__ __launch_bounds__(256) void k_sample(const float* __restrict__ v,
    const float* __restrict__ fm, float* __restrict__ o){
  __shared__ float sfm[PPB][256];
  int pixBase = blockIdx.x * PPB;
  int tid = threadIdx.x;          // channel = g*32 + ch
  int g = tid >> 5;
  #pragma unroll
  for (int i = 0; i < PPB; ++i)
    sfm[i][tid] = fm[(size_t)(pixBase + i) * 256 + tid];
  __syncthreads();
  int n = pixBase >> 12;          // all PPB pixels in same image (4096 % PPB == 0)
  const float* vb = v + (size_t)n * HWSZ * CH + tid;
  #pragma unroll
  for (int p = 0; p < PPB; ++p) {
    int hw = (pixBase + p) & 4095;
    int h = hw >> 6, w = hw & 63;
    const float* fp = sfm[p];
    float ml[9];
    float mx = -1e30f;
    #pragma unroll
    for (int k = 0; k < 9; ++k) { ml[k] = fp[144 + g*9 + k]; mx = fmaxf(mx, ml[k]); }
    float ssum = 0.f;
    #pragma unroll
    for (int k = 0; k < 9; ++k) { ml[k] = __expf(ml[k] - mx); ssum += ml[k]; }
    float acc = 0.f;
    #pragma unroll
    for (int k = 0; k < 9; ++k) {
      int dx = k/3 - 1, dy = k%3 - 1;     // dx-major per meshgrid(indexing='ij')
      float ox = fp[g*18 + k*2];
      float oy = fp[g*18 + k*2 + 1];
      float xu = (float)(w + dx) + ox;    // unpadded sampling coords
      float yu = (float)(h + dy) + oy;
      float xf = floorf(xu), yf = floorf(yu);
      float tx = xu - xf, ty = yu - yf;
      int x0 = (int)xf, y0 = (int)yf;
      int x1 = x0 + 1, y1 = y0 + 1;
      float m00 = (float)((unsigned)x0 < 64u && (unsigned)y0 < 64u);
      float m10 = (float)((unsigned)x1 < 64u && (unsigned)y0 < 64u);
      float m01 = (float)((unsigned)x0 < 64u && (unsigned)y1 < 64u);
      float m11 = (float)((unsigned)x1 < 64u && (unsigned)y1 < 64u);
      int xc0 = min(max(x0, 0), 63), xc1 = min(max(x1, 0), 63);
      int yc0 = min(max(y0, 0), 63), yc1 = min(max(y1, 0), 63);
      float v00 = vb[(size_t)((yc0 << 6) + xc0) * CH];
      float v10 = vb[(size_t)((yc0 << 6) + xc1) * CH];
      float v01 = vb[(size_t)((yc1 << 6) + xc0) * CH];
      float v11 = vb[(size_t)((yc1 << 6) + xc1) * CH];
      float w10x = tx, w0x = 1.f - tx, w1y = ty, w0y = 1.f - ty;
      float val = v00 * (w0x * w0y * m00) + v10 * (w10x * w0y * m10)
                + v01 * (w0x * w1y * m01) + v11 * (w10x * w1y * m11);
      acc = fmaf(ml[k], val, acc);
    }
    o[(size_t)(pixBase + p) * 256 + tid] = acc * (1.f / ssum);
  }
}

// ---------------- gate: out[n,c,h,w] = x[n,c,h,w] * attn[n,h,w,c] ----------------
__global__ __launch_bounds__(256) void k_gate(const float* __restrict__ x, const float* __restrict__ attn,
                                              float* __restrict__ out){
  __shared__ float t[32][33];
  int n = blockIdx.z;
  int p0 = blockIdx.x * 32;
  int c0 = blockIdx.y * 32;
  const float* an = attn + (size_t)n * HWSZ * CH;
  const float* xn = x + (size_t)n * CH * HWSZ;
  float* on = out + (size_t)n * CH * HWSZ;
  int tx = threadIdx.x, ty = threadIdx.y;
  #pragma unroll
  for (int i = 0; i < 4; ++i) {
    int p = p0 + ty + i*8;
    t[ty + i*8][tx] = an[(size_t)p * CH + c0 + tx];   // t[p_local][c_local]
  }
  __syncthreads();
  #pragma unroll
  for (int i = 0; i < 4; ++i) {
    int c = c0 + ty + i*8;
    size_t idx = (size_t)c * HWSZ + p0 + tx;
    on[idx] = xn[idx] * t[tx][ty + i*8];              // t[p_local=tx][c_local]
  }
}

extern "C" void kernel_launch(void* const* d_in, const int* in_sizes, int n_in,
                              void* d_out, int out_size, void* d_ws, size_t ws_size,
                              hipStream_t stream) {
  const float* x      = (const float*)d_in[0];
  const float* a_dw_w = (const float*)d_in[1];
  const float* a_dw_b = (const float*)d_in[2];
  const float* a_ln_g = (const float*)d_in[3];
  const float* a_ln_b = (const float*)d_in[4];
  const float* a_in_w = (const float*)d_in[5];
  const float* a_in_b = (const float*)d_in[6];
  const float* a_off_w= (const float*)d_in[7];
  const float* a_off_b= (const float*)d_in[8];
  const float* a_mk_w = (const float*)d_in[9];
  const float* a_mk_b = (const float*)d_in[10];
  const float* a_out_w= (const float*)d_in[11];
  const float* a_out_b= (const float*)d_in[12];
  const float* b_dw_w = (const float*)d_in[13];
  const float* b_dw_b = (const float*)d_in[14];
  const float* b_ln_g = (const float*)d_in[15];
  const float* b_ln_b = (const float*)d_in[16];
  const float* b_in_w = (const float*)d_in[17];
  const float* b_in_b = (const float*)d_in[18];
  const float* b_off_w= (const float*)d_in[19];
  const float* b_off_b= (const float*)d_in[20];
  const float* b_mk_w = (const float*)d_in[21];
  const float* b_mk_b = (const float*)d_in[22];
  const float* b_out_w= (const float*)d_in[23];
  const float* b_out_b= (const float*)d_in[24];
  const float* proj_w = (const float*)d_in[25];
  const float* proj_b = (const float*)d_in[26];
  float* out = (float*)d_out;

  float* ws = (float*)d_ws;
  const size_t BUF = (size_t)PIX * CH;   // 2,097,152 floats (8 MB)
  float* buf0 = ws;               // x NHWC -> later attn2
  float* buf1 = buf0 + BUF;       // f -> later proj output
  float* buf2 = buf1 + BUF;       // v
  float* buf3 = buf2 + BUF;       // fm (offset+mask logits)
  float* buf4 = buf3 + BUF;       // o (sampled)
  float* buf5 = buf4 + BUF;       // attn1
  ushort* Btw = (ushort*)(buf5 + BUF);   // 7 x 65536 bf16 weights (B^T, k-contiguous)
  float* bcatA = (float*)(Btw + 7*65536);
  float* bcatB = bcatA + 256;

  dim3 tb(32, 8);
  dim3 tgrid(HWSZ/32, CH/32, NB);
  dim3 ggrid(PIX/64, CH/64);     // 128 x 4

  k_nchw2nhwc<<<tgrid, tb, 0, stream>>>(x, buf0);
  k_prepw<<<dim3(8,8,7), tb, 0, stream>>>(a_in_w, a_off_w, a_mk_w, a_out_w,
                                          b_in_w, b_off_w, b_mk_w, b_out_w, proj_w, Btw);
  k_bias<<<1, 256, 0, stream>>>(a_off_b, a_mk_b, b_off_b, b_mk_b, bcatA, bcatB);

  // ---- layer a ----
  k_dwln<<<PIX, 256, 0, stream>>>(buf0, a_dw_w, a_dw_b, a_ln_g, a_ln_b, buf1);
  k_gemm_bf<<<ggrid, 256, 0, stream>>>(buf0, Btw + 0*65536, a_in_b, buf2);   // v
  k_gemm_bf<<<ggrid, 256, 0, stream>>>(buf1, Btw + 1*65536, bcatA, buf3);    // offsets+mask
  k_sample<<<PIX/PPB, 256, 0, stream>>>(buf2, buf3, buf4);                   // o
  k_gemm_bf<<<ggrid, 256, 0, stream>>>(buf4, Btw + 2*65536, a_out_b, buf5);  // attn1

  // ---- layer b ----
  k_dwln<<<PIX, 256, 0, stream>>>(buf5, b_dw_w, b_dw_b, b_ln_g, b_ln_b, buf1);
  k_gemm_bf<<<ggrid, 256, 0, stream>>>(buf5, Btw + 3*65536, b_in_b, buf2);   // v
  k_gemm_bf<<<ggrid, 256, 0, stream>>>(buf1, Btw + 4*65536, bcatB, buf3);    // offsets+mask
  k_sample<<<PIX/PPB, 256, 0, stream>>>(buf2, buf3, buf4);                   // o
  k_gemm_bf<<<ggrid, 256, 0, stream>>>(buf4, Btw + 5*65536, b_out_b, buf0);  // attn2

  // ---- final proj + gate ----
  k_gemm_bf<<<ggrid, 256, 0, stream>>>(buf0, Btw + 6*65536, proj_b, buf1);   // attn
  k_gate<<<tgrid, tb, 0, stream>>>(x, buf1, out);
}